// Round 1
// baseline (605.863 us; speedup 1.0000x reference)
//
#include <hip/hip_runtime.h>
#include <hip/hip_bf16.h>

#define BB 16
#define TT 2048
#define DIMC 512
#define HEADH 64

static __device__ __forceinline__ float bf2f(unsigned int lo16) {
    return __uint_as_float(lo16 << 16);
}
static __device__ __forceinline__ unsigned short f2bf(float f) {
    unsigned int x = __float_as_uint(f);
    unsigned int r = (x + 0x7fffu + ((x >> 16) & 1u)) >> 16;
    return (unsigned short)r;
}

// ---------------- Kernel A: QKV projection + rotary + scale, f32 -> bf16 ----
// Block: 256 threads. Tile: 64 t-rows x 192 outputs (q|k|v of 64 each).
// Thread (tt,hh): tt = tid>>4 owns 4 t-rows, hh = tid&15 owns 12 output rows.
// K staged in chunks of 32 to keep static LDS under 64KB.
__global__ __launch_bounds__(256) void qkv_rope_kernel(
    const float* __restrict__ x,
    const float* __restrict__ Wq, const float* __restrict__ Wk,
    const float* __restrict__ Wv,
    const float* __restrict__ fxr, const float* __restrict__ fxi,
    const float* __restrict__ fyr, const float* __restrict__ fyi,
    unsigned short* __restrict__ qo, unsigned short* __restrict__ ko,
    unsigned short* __restrict__ vo)
{
    __shared__ float xs[64][35];    // stride 35: tt-groups 140%32=12 apart -> no conflict
    __shared__ float wsh[192][35];  // hh-groups 420%32=4 apart -> 2-way (free)

    const int tid = threadIdx.x;
    const int b   = blockIdx.x >> 5;
    const int t0  = (blockIdx.x & 31) << 6;
    const int hh  = tid & 15;   // output rows hh*12 .. hh*12+11 (of 192)
    const int tt  = tid >> 4;   // t rows tt*4 .. tt*4+3 (of 64)

    float acc[4][12];
    #pragma unroll
    for (int j = 0; j < 4; ++j)
        #pragma unroll
        for (int r = 0; r < 12; ++r) acc[j][r] = 0.f;

    for (int c0 = 0; c0 < DIMC; c0 += 32) {
        __syncthreads();
        // stage x tile: 64 rows x 32 cols = 512 float4
        #pragma unroll
        for (int i = tid; i < 64 * 8; i += 256) {
            int r = i >> 3, c = (i & 7) << 2;
            float4 v4 = *(const float4*)(x + ((size_t)(b * TT + t0 + r)) * DIMC + c0 + c);
            xs[r][c + 0] = v4.x; xs[r][c + 1] = v4.y;
            xs[r][c + 2] = v4.z; xs[r][c + 3] = v4.w;
        }
        // stage W tile: 192 rows x 32 cols = 1536 float4
        #pragma unroll
        for (int i = tid; i < 192 * 8; i += 256) {
            int r = i >> 3, c = (i & 7) << 2;
            const float* Wp = (r < 64) ? Wq : (r < 128) ? Wk : Wv;
            float4 v4 = *(const float4*)(Wp + (size_t)(r & 63) * DIMC + c0 + c);
            wsh[r][c + 0] = v4.x; wsh[r][c + 1] = v4.y;
            wsh[r][c + 2] = v4.z; wsh[r][c + 3] = v4.w;
        }
        __syncthreads();
        #pragma unroll 4
        for (int c = 0; c < 32; ++c) {
            float xv[4], wv[12];
            #pragma unroll
            for (int j = 0; j < 4; ++j) xv[j] = xs[tt * 4 + j][c];
            #pragma unroll
            for (int r = 0; r < 12; ++r) wv[r] = wsh[hh * 12 + r][c];
            #pragma unroll
            for (int j = 0; j < 4; ++j)
                #pragma unroll
                for (int r = 0; r < 12; ++r)
                    acc[j][r] = fmaf(xv[j], wv[r], acc[j][r]);
        }
    }

    // epilogue: rotary on q,k; fold 1/sqrt(512) into q; store bf16
    const float qscale = 0.044194173824159216f;  // 1/sqrt(512)
    #pragma unroll
    for (int j = 0; j < 4; ++j) {
        const int t = t0 + tt * 4 + j;
        #pragma unroll
        for (int r = 0; r < 12; r += 2) {
            int gh  = hh * 12 + r;      // even; pair (gh, gh+1) never crosses a matrix boundary
            int mat = gh >> 6;          // 0=q, 1=k, 2=v
            int h   = gh & 63;          // even
            float a = acc[j][r], bb = acc[j][r + 1];
            float e0 = a, e1 = bb;
            if (mat < 2) {
                int half = h >> 5;           // 0 -> fx tables, 1 -> fy tables
                int pi   = (h & 31) >> 1;    // complex pair index 0..15
                float fr = half ? fyr[t * 16 + pi] : fxr[t * 16 + pi];
                float fi = half ? fyi[t * 16 + pi] : fxi[t * 16 + pi];
                e0 = a * fr - bb * fi;
                e1 = a * fi + bb * fr;
            }
            size_t base = ((size_t)(b * TT + t)) * HEADH + h;
            if (mat == 0) {
                qo[base]     = f2bf(e0 * qscale);
                qo[base + 1] = f2bf(e1 * qscale);
            } else if (mat == 1) {
                ko[base]     = f2bf(e0);
                ko[base + 1] = f2bf(e1);
            } else {
                vo[base]     = f2bf(e0);
                vo[base + 1] = f2bf(e1);
            }
        }
    }
}

// ---------------- Kernel B: flash attention (vector f32) --------------------
// Block: 256 threads = 64 q-rows x 4 threads (16-wide d-split each).
// K/V tiles of 64 rows staged in LDS as f32 (stride 68: b128-aligned, reads
// are 4-address wave broadcasts -> conflict-free). Online softmax with
// __any-guarded rescale.
__global__ __launch_bounds__(256) void attn_kernel(
    const unsigned short* __restrict__ qws,
    const unsigned short* __restrict__ kws,
    const unsigned short* __restrict__ vws,
    float* __restrict__ out)
{
    __shared__ float kk[64][68];
    __shared__ float vv[64][68];

    const int tid = threadIdx.x;
    const int b   = blockIdx.x >> 5;
    const int q0  = (blockIdx.x & 31) << 6;
    const int qi  = tid >> 2;          // 0..63
    const int ds  = (tid & 3) << 4;    // 0,16,32,48

    float qv[16];
    {
        const unsigned short* qp = qws + ((size_t)(b * TT + q0 + qi)) * HEADH + ds;
        #pragma unroll
        for (int j = 0; j < 16; ++j) qv[j] = bf2f((unsigned int)qp[j]);
    }
    float o[16];
    #pragma unroll
    for (int j = 0; j < 16; ++j) o[j] = 0.f;
    float m = -1e30f, l = 0.f;

    for (int k0 = 0; k0 < TT; k0 += 64) {
        __syncthreads();
        // stage 64x64 bf16 K and V tiles -> f32 LDS; 512 uint4 loads each
        #pragma unroll
        for (int i = tid; i < 64 * 8; i += 256) {
            int r = i >> 3, c = (i & 7) << 3;   // 8 bf16 per uint4
            const uint4 k4 = *(const uint4*)(kws + ((size_t)(b * TT + k0 + r)) * HEADH + c);
            const uint4 v4 = *(const uint4*)(vws + ((size_t)(b * TT + k0 + r)) * HEADH + c);
            unsigned int ku[4] = {k4.x, k4.y, k4.z, k4.w};
            unsigned int vu[4] = {v4.x, v4.y, v4.z, v4.w};
            #pragma unroll
            for (int w = 0; w < 4; ++w) {
                kk[r][c + 2 * w]     = __uint_as_float(ku[w] << 16);
                kk[r][c + 2 * w + 1] = __uint_as_float(ku[w] & 0xffff0000u);
                vv[r][c + 2 * w]     = __uint_as_float(vu[w] << 16);
                vv[r][c + 2 * w + 1] = __uint_as_float(vu[w] & 0xffff0000u);
            }
        }
        __syncthreads();

        #pragma unroll 2
        for (int kr = 0; kr < 64; ++kr) {
            float s = 0.f;
            #pragma unroll
            for (int j = 0; j < 16; ++j) s = fmaf(qv[j], kk[kr][ds + j], s);
            s += __shfl_xor(s, 1);
            s += __shfl_xor(s, 2);             // all 4 lanes of a q-row agree
            float mnew = fmaxf(m, s);
            float p = __expf(s - mnew);
            if (__any(mnew > m)) {             // rare after early tiles
                float scale = __expf(m - mnew);
                l *= scale;
                #pragma unroll
                for (int j = 0; j < 16; ++j) o[j] *= scale;
            }
            m = mnew;
            l += p;
            #pragma unroll
            for (int j = 0; j < 16; ++j) o[j] = fmaf(p, vv[kr][ds + j], o[j]);
        }
    }

    const float inv = 1.f / l;
    float* op = out + ((size_t)(b * TT + q0 + qi)) * HEADH + ds;
    #pragma unroll
    for (int j = 0; j < 4; ++j) {
        float4 v4 = make_float4(o[4 * j] * inv, o[4 * j + 1] * inv,
                                o[4 * j + 2] * inv, o[4 * j + 3] * inv);
        *(float4*)(op + 4 * j) = v4;
    }
}

extern "C" void kernel_launch(void* const* d_in, const int* in_sizes, int n_in,
                              void* d_out, int out_size, void* d_ws, size_t ws_size,
                              hipStream_t stream)
{
    const float* x   = (const float*)d_in[0];
    const float* Wq  = (const float*)d_in[1];
    const float* Wk  = (const float*)d_in[2];
    const float* Wv  = (const float*)d_in[3];
    const float* fxr = (const float*)d_in[4];
    const float* fxi = (const float*)d_in[5];
    const float* fyr = (const float*)d_in[6];
    const float* fyi = (const float*)d_in[7];
    float* out = (float*)d_out;

    unsigned short* qo = (unsigned short*)d_ws;                 // 12 MB total in d_ws
    unsigned short* ko = qo + (size_t)BB * TT * HEADH;
    unsigned short* vo = ko + (size_t)BB * TT * HEADH;

    qkv_rope_kernel<<<BB * 32, 256, 0, stream>>>(x, Wq, Wk, Wv, fxr, fxi, fyr, fyi,
                                                 qo, ko, vo);
    attn_kernel<<<BB * 32, 256, 0, stream>>>(qo, ko, vo, out);
}

// Round 2
// 244.299 us; speedup vs baseline: 2.4800x; 2.4800x over previous
//
#include <hip/hip_runtime.h>
#include <hip/hip_bf16.h>

#define BB 16
#define TT 2048
#define DIMC 512
#define HEADH 64

typedef __attribute__((ext_vector_type(8))) short short8v;   // 8 bf16 (4 VGPRs)
typedef __attribute__((ext_vector_type(4))) float f32x4;     // MFMA C/D

static __device__ __forceinline__ float bf2f(unsigned int lo16) {
    return __uint_as_float(lo16 << 16);
}
static __device__ __forceinline__ unsigned short f2bf(float f) {
    unsigned int x = __float_as_uint(f);
    unsigned int r = (x + 0x7fffu + ((x >> 16) & 1u)) >> 16;
    return (unsigned short)r;
}
static __device__ __forceinline__ unsigned int packbf(float lo, float hi) {
    return (unsigned int)f2bf(lo) | ((unsigned int)f2bf(hi) << 16);
}

// ---------------- Kernel A: QKV projection + rotary + scale, f32 -> bf16 ----
// Same structure as round-1 baseline (passed). Changes:
//  * q scale now folds log2(e) so attention can use native exp2 (v_exp_f32)
//  * V is written TRANSPOSED: vt[b][d][t], so attention's out^T = V^T * P^T
//    A-fragments are contiguous 16B loads.
__global__ __launch_bounds__(256) void qkv_rope_kernel(
    const float* __restrict__ x,
    const float* __restrict__ Wq, const float* __restrict__ Wk,
    const float* __restrict__ Wv,
    const float* __restrict__ fxr, const float* __restrict__ fxi,
    const float* __restrict__ fyr, const float* __restrict__ fyi,
    unsigned short* __restrict__ qo, unsigned short* __restrict__ ko,
    unsigned short* __restrict__ vt)
{
    __shared__ float xs[64][35];
    __shared__ float wsh[192][35];

    const int tid = threadIdx.x;
    const int b   = blockIdx.x >> 5;
    const int t0  = (blockIdx.x & 31) << 6;
    const int hh  = tid & 15;
    const int tt  = tid >> 4;

    float acc[4][12];
    #pragma unroll
    for (int j = 0; j < 4; ++j)
        #pragma unroll
        for (int r = 0; r < 12; ++r) acc[j][r] = 0.f;

    for (int c0 = 0; c0 < DIMC; c0 += 32) {
        __syncthreads();
        #pragma unroll
        for (int i = tid; i < 64 * 8; i += 256) {
            int r = i >> 3, c = (i & 7) << 2;
            float4 v4 = *(const float4*)(x + ((size_t)(b * TT + t0 + r)) * DIMC + c0 + c);
            xs[r][c + 0] = v4.x; xs[r][c + 1] = v4.y;
            xs[r][c + 2] = v4.z; xs[r][c + 3] = v4.w;
        }
        #pragma unroll
        for (int i = tid; i < 192 * 8; i += 256) {
            int r = i >> 3, c = (i & 7) << 2;
            const float* Wp = (r < 64) ? Wq : (r < 128) ? Wk : Wv;
            float4 v4 = *(const float4*)(Wp + (size_t)(r & 63) * DIMC + c0 + c);
            wsh[r][c + 0] = v4.x; wsh[r][c + 1] = v4.y;
            wsh[r][c + 2] = v4.z; wsh[r][c + 3] = v4.w;
        }
        __syncthreads();
        #pragma unroll 4
        for (int c = 0; c < 32; ++c) {
            float xv[4], wv[12];
            #pragma unroll
            for (int j = 0; j < 4; ++j) xv[j] = xs[tt * 4 + j][c];
            #pragma unroll
            for (int r = 0; r < 12; ++r) wv[r] = wsh[hh * 12 + r][c];
            #pragma unroll
            for (int j = 0; j < 4; ++j)
                #pragma unroll
                for (int r = 0; r < 12; ++r)
                    acc[j][r] = fmaf(xv[j], wv[r], acc[j][r]);
        }
    }

    // epilogue: rotary on q,k; q scaled by log2(e)/sqrt(512); store bf16
    const float qscale = 1.4426950408889634f / 22.627416997969522f;
    #pragma unroll
    for (int j = 0; j < 4; ++j) {
        const int t = t0 + tt * 4 + j;
        #pragma unroll
        for (int r = 0; r < 12; r += 2) {
            int gh  = hh * 12 + r;
            int mat = gh >> 6;          // 0=q, 1=k, 2=v
            int h   = gh & 63;          // even
            float a = acc[j][r], bb = acc[j][r + 1];
            float e0 = a, e1 = bb;
            if (mat < 2) {
                int half = h >> 5;
                int pi   = (h & 31) >> 1;
                float fr = half ? fyr[t * 16 + pi] : fxr[t * 16 + pi];
                float fi = half ? fyi[t * 16 + pi] : fxi[t * 16 + pi];
                e0 = a * fr - bb * fi;
                e1 = a * fi + bb * fr;
            }
            if (mat == 0) {
                size_t base = ((size_t)(b * TT + t)) * HEADH + h;
                qo[base]     = f2bf(e0 * qscale);
                qo[base + 1] = f2bf(e1 * qscale);
            } else if (mat == 1) {
                size_t base = ((size_t)(b * TT + t)) * HEADH + h;
                ko[base]     = f2bf(e0);
                ko[base + 1] = f2bf(e1);
            } else {
                vt[((size_t)b * HEADH + h)     * TT + t] = f2bf(e0);
                vt[((size_t)b * HEADH + h + 1) * TT + t] = f2bf(e1);
            }
        }
    }
}

// ---------------- Kernel B: MFMA flash attention ----------------------------
// One wave per block, 16 q-rows per wave, KV chunks of 64.
// Swapped QK^T: S^T = K_tile(16x64) . Q^T(64x16) via mfma_16x16x32_bf16:
//   lane holds S^T[kv=4g+r+16n][q=l&15] -> softmax per q is lane-local
//   (15 fmax) + shfl_xor(16,32) across the 4 row-groups.
// PV as out^T = V^T(16x64) . P^T(64x16); P^T re-laid C->B layout through a
// 2KB XOR-swizzled LDS buffer (b64 writes, b128 reads, conflict-free).
__global__ __launch_bounds__(64) void attn_mfma_kernel(
    const unsigned short* __restrict__ qws,   // [b][t][64] bf16, pre-scaled
    const unsigned short* __restrict__ kws,   // [b][t][64] bf16
    const unsigned short* __restrict__ vtw,   // [b][d][t]  bf16 (V^T)
    float* __restrict__ out)
{
    __shared__ unsigned int plds[16 * 32];    // P^T bf16-pair words, swizzled

    const int l   = threadIdx.x;              // 0..63
    const int q   = l & 15;
    const int g   = l >> 4;
    const int b   = blockIdx.x >> 7;
    const int q0  = (blockIdx.x & 127) << 4;
    const int swz = (q & 7) << 2;             // XOR on word-index bits 2..4

    // Q fragment (B operand): lane holds Q[q0+q][32s + 8g + 0..7]
    short8v qf[2];
    {
        const unsigned short* qp = qws + ((size_t)(b * TT + q0 + q)) * HEADH + 8 * g;
        qf[0] = *(const short8v*)(qp);
        qf[1] = *(const short8v*)(qp + 32);
    }

    f32x4 oacc[4];
    #pragma unroll
    for (int mt = 0; mt < 4; ++mt) oacc[mt] = (f32x4){0.f, 0.f, 0.f, 0.f};
    float m = -1e30f, lsum = 0.f;

    const unsigned short* kbase = kws + (size_t)b * TT * HEADH;
    const unsigned short* vbase = vtw + (size_t)b * HEADH * TT;

    for (int kv0 = 0; kv0 < TT; kv0 += 64) {
        // ---- QK^T: 4 kv-tiles x 2 k-steps ----
        f32x4 sacc[4];
        #pragma unroll
        for (int n = 0; n < 4; ++n) {
            const unsigned short* kp = kbase + (size_t)(kv0 + 16 * n + q) * HEADH + 8 * g;
            short8v k0 = *(const short8v*)(kp);
            short8v k1 = *(const short8v*)(kp + 32);
            sacc[n] = (f32x4){0.f, 0.f, 0.f, 0.f};
            sacc[n] = __builtin_amdgcn_mfma_f32_16x16x32_bf16(k0, qf[0], sacc[n], 0, 0, 0);
            sacc[n] = __builtin_amdgcn_mfma_f32_16x16x32_bf16(k1, qf[1], sacc[n], 0, 0, 0);
        }

        // ---- V^T fragments issued early: latency hides under softmax ----
        short8v vf[2][4];
        #pragma unroll
        for (int s = 0; s < 2; ++s)
            #pragma unroll
            for (int mt = 0; mt < 4; ++mt)
                vf[s][mt] = *(const short8v*)(vbase +
                    (size_t)(16 * mt + q) * TT + kv0 + 32 * s + 8 * g);

        // ---- online softmax (lane owns q-row l&15) ----
        float cmax = sacc[0][0];
        #pragma unroll
        for (int n = 0; n < 4; ++n)
            #pragma unroll
            for (int r = 0; r < 4; ++r) cmax = fmaxf(cmax, sacc[n][r]);
        cmax = fmaxf(cmax, __shfl_xor(cmax, 16));
        cmax = fmaxf(cmax, __shfl_xor(cmax, 32));
        const float mnew = fmaxf(m, cmax);

        float p[4][4];
        float psum = 0.f;
        #pragma unroll
        for (int n = 0; n < 4; ++n)
            #pragma unroll
            for (int r = 0; r < 4; ++r) {
                p[n][r] = exp2f(sacc[n][r] - mnew);   // native v_exp_f32
                psum += p[n][r];
            }
        psum += __shfl_xor(psum, 16);
        psum += __shfl_xor(psum, 32);

        const float sc = exp2f(m - mnew);             // ==1 when no new max
        if (__any(cmax > m)) {
            #pragma unroll
            for (int mt = 0; mt < 4; ++mt)
                #pragma unroll
                for (int r = 0; r < 4; ++r) oacc[mt][r] *= sc;
        }
        lsum = lsum * sc + psum;
        m = mnew;

        // ---- pack P^T to bf16 words, swizzled LDS write (b64) ----
        // word wi = 8n + 2g + rh holds kv pair (16n+4g+2rh, +1) for row q
        #pragma unroll
        for (int n = 0; n < 4; ++n) {
            uint2 w;
            w.x = packbf(p[n][0], p[n][1]);
            w.y = packbf(p[n][2], p[n][3]);
            *(uint2*)&plds[q * 32 + ((8 * n + 2 * g) ^ swz)] = w;
        }

        // ---- PV: out^T += V^T . P^T  (4 d-tiles x 2 k-steps) ----
        #pragma unroll
        for (int s = 0; s < 2; ++s) {
            short8v pb = *(const short8v*)&plds[q * 32 + ((16 * s + 4 * g) ^ swz)];
            #pragma unroll
            for (int mt = 0; mt < 4; ++mt)
                oacc[mt] = __builtin_amdgcn_mfma_f32_16x16x32_bf16(vf[s][mt], pb,
                                                                   oacc[mt], 0, 0, 0);
        }
    }

    // ---- normalize + store: oacc[mt][r] = out[q0+q][16mt+4g+r] ----
    const float inv = 1.f / lsum;
    float* op = out + ((size_t)(b * TT + q0 + q)) * HEADH;
    #pragma unroll
    for (int mt = 0; mt < 4; ++mt) {
        float4 v4 = make_float4(oacc[mt][0] * inv, oacc[mt][1] * inv,
                                oacc[mt][2] * inv, oacc[mt][3] * inv);
        *(float4*)(op + 16 * mt + 4 * g) = v4;
    }
}

extern "C" void kernel_launch(void* const* d_in, const int* in_sizes, int n_in,
                              void* d_out, int out_size, void* d_ws, size_t ws_size,
                              hipStream_t stream)
{
    const float* x   = (const float*)d_in[0];
    const float* Wq  = (const float*)d_in[1];
    const float* Wk  = (const float*)d_in[2];
    const float* Wv  = (const float*)d_in[3];
    const float* fxr = (const float*)d_in[4];
    const float* fxi = (const float*)d_in[5];
    const float* fyr = (const float*)d_in[6];
    const float* fyi = (const float*)d_in[7];
    float* out = (float*)d_out;

    unsigned short* qo = (unsigned short*)d_ws;
    unsigned short* ko = qo + (size_t)BB * TT * HEADH;
    unsigned short* vt = ko + (size_t)BB * TT * HEADH;

    qkv_rope_kernel<<<BB * 32, 256, 0, stream>>>(x, Wq, Wk, Wv, fxr, fxi, fyr, fyi,
                                                 qo, ko, vt);
    attn_mfma_kernel<<<BB * 128, 64, 0, stream>>>(qo, ko, vt, out);
}

// Round 3
// 174.385 us; speedup vs baseline: 3.4743x; 1.4009x over previous
//
#include <hip/hip_runtime.h>
#include <hip/hip_bf16.h>

#define BB 16
#define TT 2048
#define DIMC 512
#define HEADH 64

typedef __attribute__((ext_vector_type(8))) short short8v;   // 8 bf16 (4 VGPRs)
typedef __attribute__((ext_vector_type(4))) float f32x4;     // MFMA C/D

static __device__ __forceinline__ unsigned short f2bf(float f) {
    unsigned int x = __float_as_uint(f);
    unsigned int r = (x + 0x7fffu + ((x >> 16) & 1u)) >> 16;
    return (unsigned short)r;
}
static __device__ __forceinline__ unsigned int packbf(float lo, float hi) {
    return (unsigned int)f2bf(lo) | ((unsigned int)f2bf(hi) << 16);
}

union bfrag {
    unsigned int u[4];
    short8v v;
};

// ---------------- Kernel 0: W f32 -> bf16, concat [q|k|v] rows -------------
__global__ __launch_bounds__(256) void wcvt_kernel(
    const float* __restrict__ Wq, const float* __restrict__ Wk,
    const float* __restrict__ Wv, unsigned short* __restrict__ wb)
{
    const int idx = blockIdx.x * 256 + threadIdx.x;   // 12288 threads x 8 elems
    const int e   = idx << 3;                         // element in [0, 192*512)
    const int row = e >> 9, col = e & 511;
    const float* src = (row < 64) ? Wq : (row < 128) ? Wk : Wv;
    const float* p = src + (size_t)(row & 63) * DIMC + col;
    float4 a = *(const float4*)p;
    float4 b = *(const float4*)(p + 4);
    uint4 o;
    o.x = packbf(a.x, a.y); o.y = packbf(a.z, a.w);
    o.z = packbf(b.x, b.y); o.w = packbf(b.z, b.w);
    *(uint4*)(wb + e) = o;
}

// ---------------- Kernel A: MFMA QKV projection + rotary -------------------
// C^T form: C[h][t] = W(192x512) . x^T(512x32768), mfma_f32_16x16x32_bf16.
// Block = 192 threads = 3 waves, wave w = matrix (0=q,1=k,2=v).
// Wave tile: 32 t x 64 h  (2 t-subtiles x 4 h-tiles, acc = 8 f32x4).
// A-frag: W[16ht + (l&15)][k0 + 8g + j]  (contiguous short8 from wb)
// B-frag: x[t0 + 16tt2 + (l&15)][k0 + 8g + j] (f32 load -> bf16 pack)
// C: lane holds h = 16ht + 4g + r, t = t0 + 16tt2 + (l&15)
//    -> rotary pairs (even h, h+1) are IN-LANE (r=0,1 and r=2,3).
__global__ __launch_bounds__(192) void qkv_mfma_kernel(
    const float* __restrict__ x,
    const unsigned short* __restrict__ wb,
    const float* __restrict__ fxr, const float* __restrict__ fxi,
    const float* __restrict__ fyr, const float* __restrict__ fyi,
    unsigned short* __restrict__ qo, unsigned short* __restrict__ ko,
    unsigned short* __restrict__ vt)
{
    const int tid = threadIdx.x;
    const int w   = tid >> 6;          // matrix: 0=q, 1=k, 2=v
    const int l   = tid & 63;
    const int q   = l & 15;
    const int g   = l >> 4;
    const int t0  = blockIdx.x << 5;   // 32 t-rows per block (global over B*T)

    f32x4 acc[2][4];
    #pragma unroll
    for (int i = 0; i < 2; ++i)
        #pragma unroll
        for (int ht = 0; ht < 4; ++ht) acc[i][ht] = (f32x4){0.f, 0.f, 0.f, 0.f};

    const unsigned short* wm = wb + ((size_t)w * 64) * DIMC;
    const float* xr0 = x + (size_t)(t0 + q) * DIMC + 8 * g;
    const float* xr1 = x + (size_t)(t0 + 16 + q) * DIMC + 8 * g;

    #pragma unroll 4
    for (int k0 = 0; k0 < DIMC; k0 += 32) {
        float4 a0 = *(const float4*)(xr0 + k0);
        float4 b0 = *(const float4*)(xr0 + k0 + 4);
        float4 a1 = *(const float4*)(xr1 + k0);
        float4 b1 = *(const float4*)(xr1 + k0 + 4);
        bfrag x0, x1;
        x0.u[0] = packbf(a0.x, a0.y); x0.u[1] = packbf(a0.z, a0.w);
        x0.u[2] = packbf(b0.x, b0.y); x0.u[3] = packbf(b0.z, b0.w);
        x1.u[0] = packbf(a1.x, a1.y); x1.u[1] = packbf(a1.z, a1.w);
        x1.u[2] = packbf(b1.x, b1.y); x1.u[3] = packbf(b1.z, b1.w);

        short8v wf[4];
        #pragma unroll
        for (int ht = 0; ht < 4; ++ht)
            wf[ht] = *(const short8v*)(wm + (size_t)(16 * ht + q) * DIMC + k0 + 8 * g);

        #pragma unroll
        for (int ht = 0; ht < 4; ++ht) {
            acc[0][ht] = __builtin_amdgcn_mfma_f32_16x16x32_bf16(wf[ht], x0.v, acc[0][ht], 0, 0, 0);
            acc[1][ht] = __builtin_amdgcn_mfma_f32_16x16x32_bf16(wf[ht], x1.v, acc[1][ht], 0, 0, 0);
        }
    }

    // epilogue (wave-uniform branch on w)
    const float qscale = 1.4426950408889634f / 22.627416997969522f; // log2e/sqrt(512)
    #pragma unroll
    for (int tt2 = 0; tt2 < 2; ++tt2) {
        const int trow = t0 + 16 * tt2 + q;
        const int tl   = trow & (TT - 1);
        if (w == 2) {
            const int b = trow >> 11;
            #pragma unroll
            for (int ht = 0; ht < 4; ++ht) {
                const int d = 16 * ht + 4 * g;
                #pragma unroll
                for (int r = 0; r < 4; ++r)
                    vt[((size_t)(b * HEADH) + d + r) * TT + tl] = f2bf(acc[tt2][ht][r]);
            }
        } else {
            const float sc = (w == 0) ? qscale : 1.f;
            unsigned short* dst = ((w == 0) ? qo : ko) + (size_t)trow * HEADH;
            #pragma unroll
            for (int ht = 0; ht < 4; ++ht) {
                const int hbase = 16 * ht + 4 * g;          // multiple of 4
                const int half  = hbase >> 5;
                const float* frt = half ? fyr : fxr;
                const float* fit = half ? fyi : fxi;
                const int pi0 = (hbase & 31) >> 1;
                float fr0 = frt[tl * 16 + pi0],     fi0 = fit[tl * 16 + pi0];
                float fr1 = frt[tl * 16 + pi0 + 1], fi1 = fit[tl * 16 + pi0 + 1];
                float e0 = acc[tt2][ht][0] * fr0 - acc[tt2][ht][1] * fi0;
                float e1 = acc[tt2][ht][0] * fi0 + acc[tt2][ht][1] * fr0;
                float e2 = acc[tt2][ht][2] * fr1 - acc[tt2][ht][3] * fi1;
                float e3 = acc[tt2][ht][2] * fi1 + acc[tt2][ht][3] * fr1;
                uint2 ow;
                ow.x = packbf(e0 * sc, e1 * sc);
                ow.y = packbf(e2 * sc, e3 * sc);
                *(uint2*)(dst + hbase) = ow;
            }
        }
    }
}

// ---------------- Kernel B: MFMA flash attention (unchanged, verified) ------
__global__ __launch_bounds__(64) void attn_mfma_kernel(
    const unsigned short* __restrict__ qws,   // [b][t][64] bf16, pre-scaled
    const unsigned short* __restrict__ kws,   // [b][t][64] bf16
    const unsigned short* __restrict__ vtw,   // [b][d][t]  bf16 (V^T)
    float* __restrict__ out)
{
    __shared__ unsigned int plds[16 * 32];    // P^T bf16-pair words, swizzled

    const int l   = threadIdx.x;              // 0..63
    const int q   = l & 15;
    const int g   = l >> 4;
    const int b   = blockIdx.x >> 7;
    const int q0  = (blockIdx.x & 127) << 4;
    const int swz = (q & 7) << 2;             // XOR on word-index bits 2..4

    short8v qf[2];
    {
        const unsigned short* qp = qws + ((size_t)(b * TT + q0 + q)) * HEADH + 8 * g;
        qf[0] = *(const short8v*)(qp);
        qf[1] = *(const short8v*)(qp + 32);
    }

    f32x4 oacc[4];
    #pragma unroll
    for (int mt = 0; mt < 4; ++mt) oacc[mt] = (f32x4){0.f, 0.f, 0.f, 0.f};
    float m = -1e30f, lsum = 0.f;

    const unsigned short* kbase = kws + (size_t)b * TT * HEADH;
    const unsigned short* vbase = vtw + (size_t)b * HEADH * TT;

    for (int kv0 = 0; kv0 < TT; kv0 += 64) {
        f32x4 sacc[4];
        #pragma unroll
        for (int n = 0; n < 4; ++n) {
            const unsigned short* kp = kbase + (size_t)(kv0 + 16 * n + q) * HEADH + 8 * g;
            short8v k0 = *(const short8v*)(kp);
            short8v k1 = *(const short8v*)(kp + 32);
            sacc[n] = (f32x4){0.f, 0.f, 0.f, 0.f};
            sacc[n] = __builtin_amdgcn_mfma_f32_16x16x32_bf16(k0, qf[0], sacc[n], 0, 0, 0);
            sacc[n] = __builtin_amdgcn_mfma_f32_16x16x32_bf16(k1, qf[1], sacc[n], 0, 0, 0);
        }

        short8v vf[2][4];
        #pragma unroll
        for (int s = 0; s < 2; ++s)
            #pragma unroll
            for (int mt = 0; mt < 4; ++mt)
                vf[s][mt] = *(const short8v*)(vbase +
                    (size_t)(16 * mt + q) * TT + kv0 + 32 * s + 8 * g);

        float cmax = sacc[0][0];
        #pragma unroll
        for (int n = 0; n < 4; ++n)
            #pragma unroll
            for (int r = 0; r < 4; ++r) cmax = fmaxf(cmax, sacc[n][r]);
        cmax = fmaxf(cmax, __shfl_xor(cmax, 16));
        cmax = fmaxf(cmax, __shfl_xor(cmax, 32));
        const float mnew = fmaxf(m, cmax);

        float p[4][4];
        float psum = 0.f;
        #pragma unroll
        for (int n = 0; n < 4; ++n)
            #pragma unroll
            for (int r = 0; r < 4; ++r) {
                p[n][r] = exp2f(sacc[n][r] - mnew);
                psum += p[n][r];
            }
        psum += __shfl_xor(psum, 16);
        psum += __shfl_xor(psum, 32);

        const float sc = exp2f(m - mnew);
        if (__any(cmax > m)) {
            #pragma unroll
            for (int mt = 0; mt < 4; ++mt)
                #pragma unroll
                for (int r = 0; r < 4; ++r) oacc[mt][r] *= sc;
        }
        lsum = lsum * sc + psum;
        m = mnew;

        #pragma unroll
        for (int n = 0; n < 4; ++n) {
            uint2 wv;
            wv.x = packbf(p[n][0], p[n][1]);
            wv.y = packbf(p[n][2], p[n][3]);
            *(uint2*)&plds[q * 32 + ((8 * n + 2 * g) ^ swz)] = wv;
        }

        #pragma unroll
        for (int s = 0; s < 2; ++s) {
            short8v pb = *(const short8v*)&plds[q * 32 + ((16 * s + 4 * g) ^ swz)];
            #pragma unroll
            for (int mt = 0; mt < 4; ++mt)
                oacc[mt] = __builtin_amdgcn_mfma_f32_16x16x32_bf16(vf[s][mt], pb,
                                                                   oacc[mt], 0, 0, 0);
        }
    }

    const float inv = 1.f / lsum;
    float* op = out + ((size_t)(b * TT + q0 + q)) * HEADH;
    #pragma unroll
    for (int mt = 0; mt < 4; ++mt) {
        float4 v4 = make_float4(oacc[mt][0] * inv, oacc[mt][1] * inv,
                                oacc[mt][2] * inv, oacc[mt][3] * inv);
        *(float4*)(op + 16 * mt + 4 * g) = v4;
    }
}

extern "C" void kernel_launch(void* const* d_in, const int* in_sizes, int n_in,
                              void* d_out, int out_size, void* d_ws, size_t ws_size,
                              hipStream_t stream)
{
    const float* x   = (const float*)d_in[0];
    const float* Wq  = (const float*)d_in[1];
    const float* Wk  = (const float*)d_in[2];
    const float* Wv  = (const float*)d_in[3];
    const float* fxr = (const float*)d_in[4];
    const float* fxi = (const float*)d_in[5];
    const float* fyr = (const float*)d_in[6];
    const float* fyi = (const float*)d_in[7];
    float* out = (float*)d_out;

    unsigned short* qo = (unsigned short*)d_ws;                  // 4 MB
    unsigned short* ko = qo + (size_t)BB * TT * HEADH;           // 4 MB
    unsigned short* vt = ko + (size_t)BB * TT * HEADH;           // 4 MB
    unsigned short* wb = vt + (size_t)BB * TT * HEADH;           // 192 KB

    wcvt_kernel<<<48, 256, 0, stream>>>(Wq, Wk, Wv, wb);
    qkv_mfma_kernel<<<(BB * TT) / 32, 192, 0, stream>>>(x, wb, fxr, fxi, fyr, fyi,
                                                        qo, ko, vt);
    attn_mfma_kernel<<<BB * 128, 64, 0, stream>>>(qo, ko, vt, out);
}